// Round 11
// baseline (454.627 us; speedup 1.0000x reference)
//
#include <hip/hip_runtime.h>
#include <hip/hip_fp16.h>
#include <math.h>

#define D_IN  256
#define D_H   64
#define D_OUT 16

typedef _Float16 f16x8 __attribute__((ext_vector_type(8)));
typedef float    f32x4 __attribute__((ext_vector_type(4)));

// non-temporal int2 load (8B scalar, unpack) — keeps edge streams from
// evicting dirty/reused lines in L2.
__device__ __forceinline__ int2 ntload_i2(const int2* p) {
    long long r = __builtin_nontemporal_load((const long long*)p);
    int2 o;
    o.x = (int)(unsigned long long)(r & 0xffffffffLL);
    o.y = (int)(r >> 32);
    return o;
}

// ---------------------------------------------------------------------------
// GEMM1 v4 (MFMA) — verified round 9 (left top-5; was 97-106us as vector GEMM).
// ---------------------------------------------------------------------------
__global__ __launch_bounds__(256) void k_gemm1(const float* __restrict__ x,
                                               const float* __restrict__ W1,
                                               __half* __restrict__ h1h, int n) {
    __shared__ _Float16 w1t[D_H][264];   // [col][k], pad 256->264 halves
    int t = threadIdx.x;
    for (int i = t; i < D_IN * D_H; i += 256) {
        int k = i >> 6, c = i & 63;
        w1t[c][k] = (_Float16)W1[i];
    }
    __syncthreads();

    int l = t & 63, w = t >> 6;
    int lrow = l & 15, lkg = l >> 4;
    int col = w * 16 + lrow;

    f16x8 bf[8];
#pragma unroll
    for (int ks = 0; ks < 8; ++ks)
        bf[ks] = *(const f16x8*)&w1t[col][ks * 32 + lkg * 8];

    int ntiles = (n + 15) >> 4;
    for (int rt = blockIdx.x; rt < ntiles; rt += gridDim.x) {
        int rbase = rt * 16;
        int row = min(rbase + lrow, n - 1);
        const float4* xr4 = (const float4*)(x + (size_t)row * D_IN);

        float4 p[16];
#pragma unroll
        for (int ks = 0; ks < 8; ++ks) {
            p[2 * ks + 0] = xr4[ks * 8 + lkg * 2 + 0];
            p[2 * ks + 1] = xr4[ks * 8 + lkg * 2 + 1];
        }

        f32x4 acc = {0.f, 0.f, 0.f, 0.f};
#pragma unroll
        for (int ks = 0; ks < 8; ++ks) {
            f16x8 af;
            af[0] = (_Float16)p[2 * ks].x;     af[1] = (_Float16)p[2 * ks].y;
            af[2] = (_Float16)p[2 * ks].z;     af[3] = (_Float16)p[2 * ks].w;
            af[4] = (_Float16)p[2 * ks + 1].x; af[5] = (_Float16)p[2 * ks + 1].y;
            af[6] = (_Float16)p[2 * ks + 1].z; af[7] = (_Float16)p[2 * ks + 1].w;
            acc = __builtin_amdgcn_mfma_f32_16x16x32_f16(af, bf[ks], acc, 0, 0, 0);
        }

#pragma unroll
        for (int reg = 0; reg < 4; ++reg) {
            int r = rbase + lkg * 4 + reg;
            if (r < n) h1h[(size_t)r * D_H + col] = __float2half(acc[reg]);
        }
    }
}

// ---------------------------------------------------------------------------
// CSR build: histogram -> 2-level exclusive scan -> XCD-phased scatter
// ---------------------------------------------------------------------------
__global__ void k_hist(const int* __restrict__ ei, int* __restrict__ counts, int e_cnt) {
    int e = blockIdx.x * blockDim.x + threadIdx.x;
    if (e < e_cnt) atomicAdd(&counts[ei[e]], 1);  // ei[0..E) = dst row
}

__global__ __launch_bounds__(256) void k_scanA(const int* __restrict__ counts,
                                               int* __restrict__ exOut,
                                               int* __restrict__ blockSum, int n) {
    __shared__ int lds[256];
    int t = threadIdx.x;
    int base = blockIdx.x * 1024 + t * 4;
    int c0 = (base + 0 < n) ? counts[base + 0] : 0;
    int c1 = (base + 1 < n) ? counts[base + 1] : 0;
    int c2 = (base + 2 < n) ? counts[base + 2] : 0;
    int c3 = (base + 3 < n) ? counts[base + 3] : 0;
    int tsum = c0 + c1 + c2 + c3;
    lds[t] = tsum;
    __syncthreads();
    for (int off = 1; off < 256; off <<= 1) {
        int v = (t >= off) ? lds[t - off] : 0;
        __syncthreads();
        lds[t] += v;
        __syncthreads();
    }
    int exBase = lds[t] - tsum;
    if (t == 0) blockSum[blockIdx.x] = lds[255];
    if (base + 0 < n) exOut[base + 0] = exBase;
    if (base + 1 < n) exOut[base + 1] = exBase + c0;
    if (base + 2 < n) exOut[base + 2] = exBase + c0 + c1;
    if (base + 3 < n) exOut[base + 3] = exBase + c0 + c1 + c2;
}

__global__ __launch_bounds__(128) void k_scanB(const int* __restrict__ blockSum,
                                               int* __restrict__ blockOff,
                                               int* __restrict__ offsets, int nb, int n) {
    __shared__ int lds[128];
    int t = threadIdx.x;
    int v = (t < nb) ? blockSum[t] : 0;
    lds[t] = v;
    __syncthreads();
    for (int off = 1; off < 128; off <<= 1) {
        int u = (t >= off) ? lds[t - off] : 0;
        __syncthreads();
        lds[t] += u;
        __syncthreads();
    }
    if (t < nb) blockOff[t] = lds[t] - v;
    if (t == 127) offsets[n] = lds[127];
}

__global__ void k_scanC(const int* __restrict__ exOut, const int* __restrict__ blockOff,
                        int* __restrict__ offsets, int* __restrict__ cursor, int n) {
    int i = blockIdx.x * blockDim.x + threadIdx.x;
    if (i < n) {
        int v = exOut[i] + blockOff[i >> 10];
        offsets[i] = v;
        cursor[i] = v;
    }
}

// XCD-phased scatter v2: + non-temporal edge-stream loads.
// Round-10 counters: dur 75us but WRITE_SIZE still 95.5MB (~64B per 8B entry)
// -> dirty line-tails in L2 are evicted by the 19.2MB/pass read stream before
// neighbors arrive. nt loads keep the stream out of L2 so tails accumulate
// (~8 entries/line) before writeback.
__global__ __launch_bounds__(256) void k_scatter(const int* __restrict__ ei,
                                                 const float* __restrict__ vals,
                                                 int* __restrict__ cursor,
                                                 int2* __restrict__ srcval,
                                                 int e_cnt, int bucketDiv,
                                                 int blocksPerPass) {
    int pass = blockIdx.x & 7;
    int bchunk = blockIdx.x >> 3;
    int lo = pass * bucketDiv;
    int stride = blocksPerPass * 256;
    for (int e = bchunk * 256 + threadIdx.x; e < e_cnt; e += stride) {
        int d = __builtin_nontemporal_load(&ei[e]);
        if ((unsigned)(d - lo) < (unsigned)bucketDiv) {
            int s = __builtin_nontemporal_load(&ei[e_cnt + e]);
            float v = __builtin_nontemporal_load(&vals[e]);
            int p = atomicAdd(&cursor[d], 1);
            srcval[p] = make_int2(s, __float_as_int(v));
        }
    }
}

// ---------------------------------------------------------------------------
// Fused SpMM1 + ReLU + GEMM2 v2 (round-9 verified: 89 -> <75us).
// v3: sv stream loads non-temporal so they stop evicting the h1h gather
// working set (12.8MB) from L2.
// ---------------------------------------------------------------------------
__global__ __launch_bounds__(256) void k_spmm1g2(const int* __restrict__ offsets,
                                                 const int2* __restrict__ sv,
                                                 const __half* __restrict__ h1h,
                                                 const float* __restrict__ W2,
                                                 __half* __restrict__ h2h, int n) {
    __shared__ float W2s[D_H * 17];
    __shared__ float rbuf[4][D_H];
    int t = threadIdx.x;
    for (int i = t; i < D_H * D_OUT; i += 256)
        W2s[(i >> 4) * 17 + (i & 15)] = W2[i];

    int lane = t & 63, wid = t >> 6;
    int dst = blockIdx.x * 4 + wid;
    bool valid = dst < n;
    int e0 = 0, e1 = 0;
    if (valid) { e0 = offsets[dst]; e1 = offsets[dst + 1]; }

    int s = lane >> 5;           // edge slot (0/1)
    int p = lane & 31;           // feature pair -> features 2p, 2p+1
    float ax = 0.f, ay = 0.f;
    int e = e0;
    for (; e + 8 <= e1; e += 8) {
        int2 A0 = ntload_i2(&sv[e + 0 + s]);
        int2 A1 = ntload_i2(&sv[e + 2 + s]);
        int2 A2 = ntload_i2(&sv[e + 4 + s]);
        int2 A3 = ntload_i2(&sv[e + 6 + s]);
        __half2 g0 = *(const __half2*)&h1h[(size_t)A0.x * D_H + 2 * p];
        __half2 g1 = *(const __half2*)&h1h[(size_t)A1.x * D_H + 2 * p];
        __half2 g2 = *(const __half2*)&h1h[(size_t)A2.x * D_H + 2 * p];
        __half2 g3 = *(const __half2*)&h1h[(size_t)A3.x * D_H + 2 * p];
        float v0 = __int_as_float(A0.y), v1 = __int_as_float(A1.y);
        float v2 = __int_as_float(A2.y), v3 = __int_as_float(A3.y);
        ax = fmaf(v0, __low2float(g0), ax); ay = fmaf(v0, __high2float(g0), ay);
        ax = fmaf(v1, __low2float(g1), ax); ay = fmaf(v1, __high2float(g1), ay);
        ax = fmaf(v2, __low2float(g2), ax); ay = fmaf(v2, __high2float(g2), ay);
        ax = fmaf(v3, __low2float(g3), ax); ay = fmaf(v3, __high2float(g3), ay);
    }
    for (; e < e1; e += 2) {
        int ee = e + s;
        bool ok = ee < e1;
        int2 A = ntload_i2(&sv[ok ? ee : e]);
        float v = ok ? __int_as_float(A.y) : 0.f;
        __half2 g = *(const __half2*)&h1h[(size_t)A.x * D_H + 2 * p];
        ax = fmaf(v, __low2float(g), ax);
        ay = fmaf(v, __high2float(g), ay);
    }
    ax += __shfl_xor(ax, 32);
    ay += __shfl_xor(ay, 32);
    if (lane < 32) {
        rbuf[wid][2 * p + 0] = fmaxf(ax, 0.f);   // relu
        rbuf[wid][2 * p + 1] = fmaxf(ay, 0.f);
    }
    __syncthreads();

    int j = lane & 15, g = lane >> 4;
    float sacc = 0.f;
#pragma unroll
    for (int kk = 0; kk < 16; ++kk)
        sacc = fmaf(rbuf[wid][g * 16 + kk], W2s[(g * 16 + kk) * 17 + j], sacc);
    sacc += __shfl_xor(sacc, 16);
    sacc += __shfl_xor(sacc, 32);
    if (valid && lane < 16) h2h[(size_t)dst * D_OUT + j] = __float2half(sacc);
}

// ---------------------------------------------------------------------------
// SpMM2 + log_softmax v2 (round-9 verified). v3: nt sv loads.
// ---------------------------------------------------------------------------
__global__ __launch_bounds__(256) void k_spmm2(const int* __restrict__ offsets,
                                               const int2* __restrict__ sv,
                                               const __half* __restrict__ h2h,
                                               float* __restrict__ out, int n) {
    int t = threadIdx.x;
    int lane = t & 63, wid = t >> 6;
    int dst = blockIdx.x * 4 + wid;
    if (dst >= n) return;
    int e0 = offsets[dst], e1 = offsets[dst + 1];

    int s = lane >> 3;           // edge slot (0..7)
    int p = lane & 7;            // feature pair -> features 2p, 2p+1
    float ax = 0.f, ay = 0.f;
    int e = e0;
    for (; e + 16 <= e1; e += 16) {
        int2 A0 = ntload_i2(&sv[e + s]);
        int2 A1 = ntload_i2(&sv[e + 8 + s]);
        __half2 g0 = *(const __half2*)&h2h[(size_t)A0.x * D_OUT + 2 * p];
        __half2 g1 = *(const __half2*)&h2h[(size_t)A1.x * D_OUT + 2 * p];
        float v0 = __int_as_float(A0.y), v1 = __int_as_float(A1.y);
        ax = fmaf(v0, __low2float(g0), ax); ay = fmaf(v0, __high2float(g0), ay);
        ax = fmaf(v1, __low2float(g1), ax); ay = fmaf(v1, __high2float(g1), ay);
    }
    for (; e + 8 <= e1; e += 8) {
        int2 A = ntload_i2(&sv[e + s]);
        __half2 g = *(const __half2*)&h2h[(size_t)A.x * D_OUT + 2 * p];
        float v = __int_as_float(A.y);
        ax = fmaf(v, __low2float(g), ax);
        ay = fmaf(v, __high2float(g), ay);
    }
    {
        int ee = e + s;
        if (ee < e1) {
            int2 A = ntload_i2(&sv[ee]);
            __half2 g = *(const __half2*)&h2h[(size_t)A.x * D_OUT + 2 * p];
            float v = __int_as_float(A.y);
            ax = fmaf(v, __low2float(g), ax);
            ay = fmaf(v, __high2float(g), ay);
        }
    }
    ax += __shfl_xor(ax, 8);  ax += __shfl_xor(ax, 16); ax += __shfl_xor(ax, 32);
    ay += __shfl_xor(ay, 8);  ay += __shfl_xor(ay, 16); ay += __shfl_xor(ay, 32);
    float m = fmaxf(ax, ay);
    m = fmaxf(m, __shfl_xor(m, 1));
    m = fmaxf(m, __shfl_xor(m, 2));
    m = fmaxf(m, __shfl_xor(m, 4));
    float sum = expf(ax - m) + expf(ay - m);
    sum += __shfl_xor(sum, 1);
    sum += __shfl_xor(sum, 2);
    sum += __shfl_xor(sum, 4);
    float lg = m + logf(sum);
    if (lane < 8) {
        float2 o = make_float2(ax - lg, ay - lg);
        *(float2*)&out[(size_t)dst * D_OUT + 2 * p] = o;
    }
}

// ---------------------------------------------------------------------------
extern "C" void kernel_launch(void* const* d_in, const int* in_sizes, int n_in,
                              void* d_out, int out_size, void* d_ws, size_t ws_size,
                              hipStream_t stream) {
    const float* x  = (const float*)d_in[0];
    const float* W1 = (const float*)d_in[1];
    const float* W2 = (const float*)d_in[2];
    const float* ev = (const float*)d_in[3];
    const int*   ei = (const int*)d_in[4];
    float* out = (float*)d_out;

    int n     = in_sizes[0] / D_IN;  // 100000
    int e_cnt = in_sizes[3];         // 1600000

    int2*   srcval = (int2*)d_ws;                       // e_cnt
    __half* h1h    = (__half*)(srcval + e_cnt);         // n*64
    __half* h2h    = h1h + (size_t)n * D_H;             // n*16
    int* counts    = (int*)(h2h + (size_t)n * D_OUT);   // n
    int* exOut     = counts + n;                        // n
    int* blockSum  = exOut + n;                         // <=128
    int* blockOff  = blockSum + 128;                    // <=128
    int* offsets   = blockOff + 128;                    // n+1
    int* cursor    = offsets + n + 1;                   // n

    hipMemsetAsync(counts, 0, (size_t)n * sizeof(int), stream);

    int nb_scan = (n + 1023) / 1024;
    int bucketDiv = (n + 7) / 8;         // dst range per XCD pass
    int blocksPerPass = 256;             // grid = 8*256 = 2048 blocks

    k_gemm1  <<<1024, 256, 0, stream>>>(x, W1, h1h, n);
    k_hist   <<<(e_cnt + 255) / 256, 256, 0, stream>>>(ei, counts, e_cnt);
    k_scanA  <<<nb_scan, 256, 0, stream>>>(counts, exOut, blockSum, n);
    k_scanB  <<<1, 128, 0, stream>>>(blockSum, blockOff, offsets, nb_scan, n);
    k_scanC  <<<(n + 255) / 256, 256, 0, stream>>>(exOut, blockOff, offsets, cursor, n);
    k_scatter<<<8 * blocksPerPass, 256, 0, stream>>>(ei, ev, cursor, srcval, e_cnt,
                                                     bucketDiv, blocksPerPass);
    k_spmm1g2<<<(n + 3) / 4, 256, 0, stream>>>(offsets, srcval, h1h, W2, h2h, n);
    k_spmm2  <<<(n + 3) / 4, 256, 0, stream>>>(offsets, srcval, h2h, out, n);
}

// Round 13
// 430.915 us; speedup vs baseline: 1.0550x; 1.0550x over previous
//
#include <hip/hip_runtime.h>
#include <hip/hip_fp16.h>
#include <math.h>

#define D_IN  256
#define D_H   64
#define D_OUT 16

typedef _Float16 f16x8 __attribute__((ext_vector_type(8)));
typedef float    f32x4 __attribute__((ext_vector_type(4)));

// ---------------------------------------------------------------------------
// GEMM1 v4 (MFMA) — verified round 9 (left top-5; was 97-106us as vector GEMM).
// ---------------------------------------------------------------------------
__global__ __launch_bounds__(256) void k_gemm1(const float* __restrict__ x,
                                               const float* __restrict__ W1,
                                               __half* __restrict__ h1h, int n) {
    __shared__ _Float16 w1t[D_H][264];   // [col][k], pad 256->264 halves
    int t = threadIdx.x;
    for (int i = t; i < D_IN * D_H; i += 256) {
        int k = i >> 6, c = i & 63;
        w1t[c][k] = (_Float16)W1[i];
    }
    __syncthreads();

    int l = t & 63, w = t >> 6;
    int lrow = l & 15, lkg = l >> 4;
    int col = w * 16 + lrow;

    f16x8 bf[8];
#pragma unroll
    for (int ks = 0; ks < 8; ++ks)
        bf[ks] = *(const f16x8*)&w1t[col][ks * 32 + lkg * 8];

    int ntiles = (n + 15) >> 4;
    for (int rt = blockIdx.x; rt < ntiles; rt += gridDim.x) {
        int rbase = rt * 16;
        int row = min(rbase + lrow, n - 1);
        const float4* xr4 = (const float4*)(x + (size_t)row * D_IN);

        float4 p[16];
#pragma unroll
        for (int ks = 0; ks < 8; ++ks) {
            p[2 * ks + 0] = xr4[ks * 8 + lkg * 2 + 0];
            p[2 * ks + 1] = xr4[ks * 8 + lkg * 2 + 1];
        }

        f32x4 acc = {0.f, 0.f, 0.f, 0.f};
#pragma unroll
        for (int ks = 0; ks < 8; ++ks) {
            f16x8 af;
            af[0] = (_Float16)p[2 * ks].x;     af[1] = (_Float16)p[2 * ks].y;
            af[2] = (_Float16)p[2 * ks].z;     af[3] = (_Float16)p[2 * ks].w;
            af[4] = (_Float16)p[2 * ks + 1].x; af[5] = (_Float16)p[2 * ks + 1].y;
            af[6] = (_Float16)p[2 * ks + 1].z; af[7] = (_Float16)p[2 * ks + 1].w;
            acc = __builtin_amdgcn_mfma_f32_16x16x32_f16(af, bf[ks], acc, 0, 0, 0);
        }

#pragma unroll
        for (int reg = 0; reg < 4; ++reg) {
            int r = rbase + lkg * 4 + reg;
            if (r < n) h1h[(size_t)r * D_H + col] = __float2half(acc[reg]);
        }
    }
}

// ---------------------------------------------------------------------------
// CSR build: histogram -> 2-level exclusive scan -> XCD-phased scatter
// ---------------------------------------------------------------------------
__global__ void k_hist(const int* __restrict__ ei, int* __restrict__ counts, int e_cnt) {
    int e = blockIdx.x * blockDim.x + threadIdx.x;
    if (e < e_cnt) atomicAdd(&counts[ei[e]], 1);  // ei[0..E) = dst row
}

__global__ __launch_bounds__(256) void k_scanA(const int* __restrict__ counts,
                                               int* __restrict__ exOut,
                                               int* __restrict__ blockSum, int n) {
    __shared__ int lds[256];
    int t = threadIdx.x;
    int base = blockIdx.x * 1024 + t * 4;
    int c0 = (base + 0 < n) ? counts[base + 0] : 0;
    int c1 = (base + 1 < n) ? counts[base + 1] : 0;
    int c2 = (base + 2 < n) ? counts[base + 2] : 0;
    int c3 = (base + 3 < n) ? counts[base + 3] : 0;
    int tsum = c0 + c1 + c2 + c3;
    lds[t] = tsum;
    __syncthreads();
    for (int off = 1; off < 256; off <<= 1) {
        int v = (t >= off) ? lds[t - off] : 0;
        __syncthreads();
        lds[t] += v;
        __syncthreads();
    }
    int exBase = lds[t] - tsum;
    if (t == 0) blockSum[blockIdx.x] = lds[255];
    if (base + 0 < n) exOut[base + 0] = exBase;
    if (base + 1 < n) exOut[base + 1] = exBase + c0;
    if (base + 2 < n) exOut[base + 2] = exBase + c0 + c1;
    if (base + 3 < n) exOut[base + 3] = exBase + c0 + c1 + c2;
}

__global__ __launch_bounds__(128) void k_scanB(const int* __restrict__ blockSum,
                                               int* __restrict__ blockOff,
                                               int* __restrict__ offsets, int nb, int n) {
    __shared__ int lds[128];
    int t = threadIdx.x;
    int v = (t < nb) ? blockSum[t] : 0;
    lds[t] = v;
    __syncthreads();
    for (int off = 1; off < 128; off <<= 1) {
        int u = (t >= off) ? lds[t - off] : 0;
        __syncthreads();
        lds[t] += u;
        __syncthreads();
    }
    if (t < nb) blockOff[t] = lds[t] - v;
    if (t == 127) offsets[n] = lds[127];
}

__global__ void k_scanC(const int* __restrict__ exOut, const int* __restrict__ blockOff,
                        int* __restrict__ offsets, int* __restrict__ cursor, int n) {
    int i = blockIdx.x * blockDim.x + threadIdx.x;
    if (i < n) {
        int v = exOut[i] + blockOff[i >> 10];
        offsets[i] = v;
        cursor[i] = v;
    }
}

// XCD-phased scatter + nt edge-stream loads (r11: neutral-or-better; the r11
// regression was attributed to nt on sv in the SpMMs, reverted there).
__global__ __launch_bounds__(256) void k_scatter(const int* __restrict__ ei,
                                                 const float* __restrict__ vals,
                                                 int* __restrict__ cursor,
                                                 int2* __restrict__ srcval,
                                                 int e_cnt, int bucketDiv,
                                                 int blocksPerPass) {
    int pass = blockIdx.x & 7;
    int bchunk = blockIdx.x >> 3;
    int lo = pass * bucketDiv;
    int stride = blocksPerPass * 256;
    for (int e = bchunk * 256 + threadIdx.x; e < e_cnt; e += stride) {
        int d = __builtin_nontemporal_load(&ei[e]);
        if ((unsigned)(d - lo) < (unsigned)bucketDiv) {
            int s = __builtin_nontemporal_load(&ei[e_cnt + e]);
            float v = __builtin_nontemporal_load(&vals[e]);
            int p = atomicAdd(&cursor[d], 1);
            srcval[p] = make_int2(s, __float_as_int(v));
        }
    }
}

// unpack 8B (4 fp16 features) and accumulate
#define ACC4(v, gi)                                                          \
    {                                                                        \
        __half2 u01 = *(__half2*)&(gi).x;                                    \
        __half2 u23 = *(__half2*)&(gi).y;                                    \
        ax = fmaf((v), __low2float(u01), ax);                                \
        ay = fmaf((v), __high2float(u01), ay);                               \
        az = fmaf((v), __low2float(u23), az);                                \
        aw = fmaf((v), __high2float(u23), aw);                               \
    }

// ---------------------------------------------------------------------------
// Fused SpMM1 + ReLU + GEMM2 v4: 8B gathers, 4 edges per load instruction.
// r11 counters (v3): 87us, VALUBusy 34%, HBM 13% -> latency-bound at ~4
// instr/edge. Lane = edge-slot (l>>4) x feature-quad (l&15): one int2 gather
// covers 4 edges/instr and a 16-lane group reads a full 128B h1h row.
// ~2 instr/edge; x4-batched main loop keeps 4 gathers in flight.
// nt on sv REVERTED (r11: +13us — sv is L2-hot from scatter's writes).
// ---------------------------------------------------------------------------
__global__ __launch_bounds__(256) void k_spmm1g2(const int* __restrict__ offsets,
                                                 const int2* __restrict__ sv,
                                                 const __half* __restrict__ h1h,
                                                 const float* __restrict__ W2,
                                                 __half* __restrict__ h2h, int n) {
    __shared__ float W2s[D_H * 17];
    __shared__ float rbuf[4][D_H];
    int t = threadIdx.x;
    for (int i = t; i < D_H * D_OUT; i += 256)
        W2s[(i >> 4) * 17 + (i & 15)] = W2[i];

    int lane = t & 63, wid = t >> 6;
    int dst = blockIdx.x * 4 + wid;
    bool valid = dst < n;
    int e0 = 0, e1 = 0;
    if (valid) { e0 = offsets[dst]; e1 = offsets[dst + 1]; }

    int s = lane >> 4;           // edge slot (0..3)
    int q = lane & 15;           // feature quad -> features 4q..4q+3
    float ax = 0.f, ay = 0.f, az = 0.f, aw = 0.f;
    int e = e0;
    for (; e + 16 <= e1; e += 16) {   // 16 edges: 4 sv loads + 4 gathers in flight
        int2 A0 = sv[e + 0 + s];
        int2 A1 = sv[e + 4 + s];
        int2 A2 = sv[e + 8 + s];
        int2 A3 = sv[e + 12 + s];
        int2 g0 = *(const int2*)&h1h[(size_t)A0.x * D_H + 4 * q];
        int2 g1 = *(const int2*)&h1h[(size_t)A1.x * D_H + 4 * q];
        int2 g2 = *(const int2*)&h1h[(size_t)A2.x * D_H + 4 * q];
        int2 g3 = *(const int2*)&h1h[(size_t)A3.x * D_H + 4 * q];
        float v0 = __int_as_float(A0.y), v1 = __int_as_float(A1.y);
        float v2 = __int_as_float(A2.y), v3 = __int_as_float(A3.y);
        ACC4(v0, g0); ACC4(v1, g1); ACC4(v2, g2); ACC4(v3, g3);
    }
    for (; e + 4 <= e1; e += 4) {
        int2 A = sv[e + s];
        int2 g = *(const int2*)&h1h[(size_t)A.x * D_H + 4 * q];
        float v = __int_as_float(A.y);
        ACC4(v, g);
    }
    {   // tail <4 edges, per-slot guard (loads only under the guard)
        int ee = e + s;
        if (ee < e1) {
            int2 A = sv[ee];
            int2 g = *(const int2*)&h1h[(size_t)A.x * D_H + 4 * q];
            float v = __int_as_float(A.y);
            ACC4(v, g);
        }
    }
    // reduce across the 4 edge slots (lane bits 4,5)
    ax += __shfl_xor(ax, 16); ax += __shfl_xor(ax, 32);
    ay += __shfl_xor(ay, 16); ay += __shfl_xor(ay, 32);
    az += __shfl_xor(az, 16); az += __shfl_xor(az, 32);
    aw += __shfl_xor(aw, 16); aw += __shfl_xor(aw, 32);
    if (lane < 16) {
        rbuf[wid][4 * q + 0] = fmaxf(ax, 0.f);   // relu
        rbuf[wid][4 * q + 1] = fmaxf(ay, 0.f);
        rbuf[wid][4 * q + 2] = fmaxf(az, 0.f);
        rbuf[wid][4 * q + 3] = fmaxf(aw, 0.f);
    }
    __syncthreads();

    // GEMM2 epilogue: h2[dst][j] = sum_k rbuf[k] * W2[k][j]
    int j = lane & 15, g = lane >> 4;
    float sacc = 0.f;
#pragma unroll
    for (int kk = 0; kk < 16; ++kk)
        sacc = fmaf(rbuf[wid][g * 16 + kk], W2s[(g * 16 + kk) * 17 + j], sacc);
    sacc += __shfl_xor(sacc, 16);
    sacc += __shfl_xor(sacc, 32);
    if (valid && lane < 16) h2h[(size_t)dst * D_OUT + j] = __float2half(sacc);
}

// ---------------------------------------------------------------------------
// SpMM2 + log_softmax v3: 16 edge-slots x 4 feature-quads -> one int2 gather
// covers 16 edges/instr (full 32B h2h row per 4-lane group). nt reverted.
// ---------------------------------------------------------------------------
__global__ __launch_bounds__(256) void k_spmm2(const int* __restrict__ offsets,
                                               const int2* __restrict__ sv,
                                               const __half* __restrict__ h2h,
                                               float* __restrict__ out, int n) {
    int t = threadIdx.x;
    int lane = t & 63, wid = t >> 6;
    int dst = blockIdx.x * 4 + wid;
    if (dst >= n) return;
    int e0 = offsets[dst], e1 = offsets[dst + 1];

    int s = lane >> 2;           // edge slot (0..15)
    int q = lane & 3;            // feature quad -> features 4q..4q+3
    float ax = 0.f, ay = 0.f, az = 0.f, aw = 0.f;
    int e = e0;
    for (; e + 32 <= e1; e += 32) {   // 2 batches in flight
        int2 A0 = sv[e + s];
        int2 A1 = sv[e + 16 + s];
        int2 g0 = *(const int2*)&h2h[(size_t)A0.x * D_OUT + 4 * q];
        int2 g1 = *(const int2*)&h2h[(size_t)A1.x * D_OUT + 4 * q];
        float v0 = __int_as_float(A0.y), v1 = __int_as_float(A1.y);
        ACC4(v0, g0); ACC4(v1, g1);
    }
    for (; e + 16 <= e1; e += 16) {
        int2 A = sv[e + s];
        int2 g = *(const int2*)&h2h[(size_t)A.x * D_OUT + 4 * q];
        float v = __int_as_float(A.y);
        ACC4(v, g);
    }
    {   // tail <16 edges, per-slot guard
        int ee = e + s;
        if (ee < e1) {
            int2 A = sv[ee];
            int2 g = *(const int2*)&h2h[(size_t)A.x * D_OUT + 4 * q];
            float v = __int_as_float(A.y);
            ACC4(v, g);
        }
    }
    // reduce across 16 edge slots (lane bits 2..5)
    ax += __shfl_xor(ax, 4); ax += __shfl_xor(ax, 8); ax += __shfl_xor(ax, 16); ax += __shfl_xor(ax, 32);
    ay += __shfl_xor(ay, 4); ay += __shfl_xor(ay, 8); ay += __shfl_xor(ay, 16); ay += __shfl_xor(ay, 32);
    az += __shfl_xor(az, 4); az += __shfl_xor(az, 8); az += __shfl_xor(az, 16); az += __shfl_xor(az, 32);
    aw += __shfl_xor(aw, 4); aw += __shfl_xor(aw, 8); aw += __shfl_xor(aw, 16); aw += __shfl_xor(aw, 32);
    // log_softmax across 16 features (quads in lanes q=0..3)
    float m = fmaxf(fmaxf(ax, ay), fmaxf(az, aw));
    m = fmaxf(m, __shfl_xor(m, 1));
    m = fmaxf(m, __shfl_xor(m, 2));
    float sum = expf(ax - m) + expf(ay - m) + expf(az - m) + expf(aw - m);
    sum += __shfl_xor(sum, 1);
    sum += __shfl_xor(sum, 2);
    float lg = m + logf(sum);
    if (lane < 4) {
        float4 o = make_float4(ax - lg, ay - lg, az - lg, aw - lg);
        *(float4*)&out[(size_t)dst * D_OUT + 4 * q] = o;
    }
}

// ---------------------------------------------------------------------------
extern "C" void kernel_launch(void* const* d_in, const int* in_sizes, int n_in,
                              void* d_out, int out_size, void* d_ws, size_t ws_size,
                              hipStream_t stream) {
    const float* x  = (const float*)d_in[0];
    const float* W1 = (const float*)d_in[1];
    const float* W2 = (const float*)d_in[2];
    const float* ev = (const float*)d_in[3];
    const int*   ei = (const int*)d_in[4];
    float* out = (float*)d_out;

    int n     = in_sizes[0] / D_IN;  // 100000
    int e_cnt = in_sizes[3];         // 1600000

    int2*   srcval = (int2*)d_ws;                       // e_cnt
    __half* h1h    = (__half*)(srcval + e_cnt);         // n*64
    __half* h2h    = h1h + (size_t)n * D_H;             // n*16
    int* counts    = (int*)(h2h + (size_t)n * D_OUT);   // n
    int* exOut     = counts + n;                        // n
    int* blockSum  = exOut + n;                         // <=128
    int* blockOff  = blockSum + 128;                    // <=128
    int* offsets   = blockOff + 128;                    // n+1
    int* cursor    = offsets + n + 1;                   // n

    hipMemsetAsync(counts, 0, (size_t)n * sizeof(int), stream);

    int nb_scan = (n + 1023) / 1024;
    int bucketDiv = (n + 7) / 8;         // dst range per XCD pass
    int blocksPerPass = 256;             // grid = 8*256 = 2048 blocks

    k_gemm1  <<<1024, 256, 0, stream>>>(x, W1, h1h, n);
    k_hist   <<<(e_cnt + 255) / 256, 256, 0, stream>>>(ei, counts, e_cnt);
    k_scanA  <<<nb_scan, 256, 0, stream>>>(counts, exOut, blockSum, n);
    k_scanB  <<<1, 128, 0, stream>>>(blockSum, blockOff, offsets, nb_scan, n);
    k_scanC  <<<(n + 255) / 256, 256, 0, stream>>>(exOut, blockOff, offsets, cursor, n);
    k_scatter<<<8 * blocksPerPass, 256, 0, stream>>>(ei, ev, cursor, srcval, e_cnt,
                                                     bucketDiv, blocksPerPass);
    k_spmm1g2<<<(n + 3) / 4, 256, 0, stream>>>(offsets, srcval, h1h, W2, h2h, n);
    k_spmm2  <<<(n + 3) / 4, 256, 0, stream>>>(offsets, srcval, h2h, out, n);
}